// Round 8
// baseline (134.797 us; speedup 1.0000x reference)
//
#include <hip/hip_runtime.h>

// R8: attack the measured anomaly — kC's L3-warm emb re-read runs at ~2 TB/s
// while kA's cold HBM read of the same bytes runs at 6.3 TB/s (R5/R6/R7
// algebra: F=85, kA=12.1, kB=2, kC=32-33 in BOTH gather- and LDS-based
// forms). Fix: non-temporal emb loads in kA (read-once, don't allocate in
// cache) and in kC (stream cold from HBM at full rate). kC also stages
// inv_n in LDS and processes channels in 4-wide steps. Per-pixel fmaf
// order identical to R0 (c ascending, same accumulators) -> bit-identical.

#define C_SEG 4096
#define E_CH 16
#define NE_EDGES 16384
#define P_PIX (1024 * 1024)
#define NCHUNK 32
#define CHUNK_PIX (P_PIX / NCHUNK)   // 32768
#define SCALE 262144.0f              // 2^18 fixed point
#define INV_SCALE (1.0f / 262144.0f)

typedef float v4f __attribute__((ext_vector_type(4)));
__device__ __forceinline__ float4 ntload4(const float* p) {
    v4f r = __builtin_nontemporal_load((const v4f*)p);
    return make_float4(r.x, r.y, r.z, r.w);
}

// ws layout (byte offsets):
//   0x000000  sums_part[16][32][4096] f32    8 MB
//   0x800000  cnt_part[32][4096]      f32  512 KB
//   0x880000  mh[2][4096][8]          f32  256 KB  (UNnormalized sums, two
//                                                   channel-half tables)
//   0x8C0000  inv_n[4096]             f32   16 KB
//   0x8C4000  part[256]               f32    1 KB
//   0x8C5000  counter                 u32    4 B

__global__ __launch_bounds__(512) void kA(const float* __restrict__ emb,
                                          const int* __restrict__ seg,
                                          float* __restrict__ sums_part,
                                          float* __restrict__ cnt_part) {
    __shared__ int bins[C_SEG];  // 16 KB
    const int chunk = blockIdx.x;
    const int g = blockIdx.y;
    const int t = threadIdx.x;
    const int base = chunk * CHUNK_PIX;

    for (int i = t; i < C_SEG; i += 512) bins[i] = 0;
    __syncthreads();

    if (g == 16) {
        for (int it = 0; it < 16; ++it) {
            const int idx = base + (it * 512 + t) * 4;
            const int4 s4 = *(const int4*)(seg + idx);
            atomicAdd(&bins[s4.x], 1);
            atomicAdd(&bins[s4.y], 1);
            atomicAdd(&bins[s4.z], 1);
            atomicAdd(&bins[s4.w], 1);
        }
        __syncthreads();
        float* cd = cnt_part + (size_t)chunk * C_SEG;
        for (int i = t; i < C_SEG; i += 512) cd[i] = (float)bins[i];
    } else {
        const float* ec = emb + (size_t)g * P_PIX;
        for (int it = 0; it < 16; ++it) {
            const int idx = base + (it * 512 + t) * 4;
            const int4 s4 = *(const int4*)(seg + idx);
            const float4 v = ntload4(ec + idx);  // read-once: don't cache
            atomicAdd(&bins[s4.x], __float2int_rn(v.x * SCALE));
            atomicAdd(&bins[s4.y], __float2int_rn(v.y * SCALE));
            atomicAdd(&bins[s4.z], __float2int_rn(v.z * SCALE));
            atomicAdd(&bins[s4.w], __float2int_rn(v.w * SCALE));
        }
        __syncthreads();
        float* dst = sums_part + ((size_t)g * NCHUNK + chunk) * C_SEG;
        for (int i = t; i < C_SEG; i += 512)
            dst[i] = (float)bins[i] * INV_SCALE;
    }
}

__global__ __launch_bounds__(256) void kB(const float* __restrict__ sums_part,
                                          const float* __restrict__ cnt_part,
                                          float* __restrict__ mh,
                                          float* __restrict__ inv_n,
                                          unsigned int* __restrict__ counter) {
    const int vb = blockIdx.x, t = threadIdx.x;
    if (vb == 0 && t == 0) counter[0] = 0u;
    if (vb < 256) {
        const int c = vb >> 4;
        const int s = (vb & 15) * 256 + t;
        const float* src = sums_part + (size_t)c * NCHUNK * C_SEG + s;
        float acc = 0.0f;
#pragma unroll
        for (int k = 0; k < NCHUNK; ++k) acc += src[(size_t)k * C_SEG];
        mh[(size_t)(c >> 3) * (C_SEG * 8) + s * 8 + (c & 7)] = acc;
    } else {
        const int s = (vb - 256) * 256 + t;
        float acc = 0.0f;
#pragma unroll
        for (int k = 0; k < NCHUNK; ++k) acc += cnt_part[(size_t)k * C_SEG + s];
        inv_n[s] = 1.0f / fmaxf(acc, 1.0f);
    }
}

// ---------------------------------------------------------------------------
// kC: 256 blocks x 1024 threads, 4 px/thread. Mean half-tables staged in
// 128 KB LDS (two phases); inv_n staged in 16 KB LDS; emb streamed with
// NON-TEMPORAL loads in 4-channel steps. fmaf order = R0 (bit-identical).
// kF fused via last-block ticket.
// ---------------------------------------------------------------------------
__global__ __launch_bounds__(1024) void kC(const float* __restrict__ emb,
                                           const int* __restrict__ seg,
                                           const int* __restrict__ edges,
                                           const float* __restrict__ w,
                                           const float* __restrict__ mh,
                                           const float* __restrict__ inv_n,
                                           float* __restrict__ part,
                                           float* __restrict__ out,
                                           unsigned int* __restrict__ counter) {
    __shared__ float mtab[C_SEG * 8];  // 128 KB
    __shared__ float invs[C_SEG];      // 16 KB
    __shared__ float red[16];
    __shared__ unsigned int tick;
    const int b = blockIdx.x, t = threadIdx.x;
    const int q = b * 1024 + t;  // quad index, 262144 total
    const int4 s4 = *(const int4*)(seg + q * 4);

    // stage inv_n once (coalesced 16 KB)
    ((float4*)invs)[t] = ((const float4*)inv_n)[t];

    float dx = 0.f, dy = 0.f, dz = 0.f, dw = 0.f;

#pragma unroll
    for (int h = 0; h < 2; ++h) {
        {   // stage mean half h (coalesced 128 KB from L2)
            const float4* src = (const float4*)(mh + (size_t)h * C_SEG * 8);
            float4* dst = (float4*)mtab;
#pragma unroll
            for (int i = 0; i < 8; ++i) dst[t + i * 1024] = src[t + i * 1024];
        }
        __syncthreads();
#pragma unroll
        for (int j = 0; j < 2; ++j) {
            const int c0 = h * 8 + j * 4;
            // 4 channel streams, non-temporal (cold HBM path)
            const float4 e0 = ntload4(emb + (size_t)(c0 + 0) * P_PIX + 4 * q);
            const float4 e1 = ntload4(emb + (size_t)(c0 + 1) * P_PIX + 4 * q);
            const float4 e2 = ntload4(emb + (size_t)(c0 + 2) * P_PIX + 4 * q);
            const float4 e3 = ntload4(emb + (size_t)(c0 + 3) * P_PIX + 4 * q);
            const float4 ma = ((const float4*)(mtab + s4.x * 8))[j];
            const float4 mb = ((const float4*)(mtab + s4.y * 8))[j];
            const float4 mc = ((const float4*)(mtab + s4.z * 8))[j];
            const float4 md = ((const float4*)(mtab + s4.w * 8))[j];
            // channels c0..c0+3 ascending; per channel: dx,dy,dz,dw (= R0 order)
            dx = fmaf(e0.x, ma.x, dx); dy = fmaf(e0.y, mb.x, dy);
            dz = fmaf(e0.z, mc.x, dz); dw = fmaf(e0.w, md.x, dw);
            dx = fmaf(e1.x, ma.y, dx); dy = fmaf(e1.y, mb.y, dy);
            dz = fmaf(e1.z, mc.y, dz); dw = fmaf(e1.w, md.y, dw);
            dx = fmaf(e2.x, ma.z, dx); dy = fmaf(e2.y, mb.z, dy);
            dz = fmaf(e2.z, mc.z, dz); dw = fmaf(e2.w, md.z, dw);
            dx = fmaf(e3.x, ma.w, dx); dy = fmaf(e3.y, mb.w, dy);
            dz = fmaf(e3.z, mc.w, dz); dw = fmaf(e3.w, md.w, dw);
        }
        __syncthreads();
    }

    const float inx = invs[s4.x], iny = invs[s4.y];
    const float inz = invs[s4.z], inw = invs[s4.w];
    float v = (fmaxf(0.5f - inx * dx, 0.0f) * inx +
               fmaxf(0.5f - iny * dy, 0.0f) * iny +
               fmaxf(0.5f - inz * dz, 0.0f) * inz +
               fmaxf(0.5f - inw * dw, 0.0f) * inw) *
              (1.0f / (float)C_SEG);

    if (t < 64) {  // 64 edges per block, mh rows from L2 (256 KB resident)
        const int e2 = b * 64 + t;
        const int u = edges[e2];
        const int vv = edges[NE_EDGES + e2];
        const float4* mu0 = (const float4*)(mh + u * 8);
        const float4* mv0 = (const float4*)(mh + vv * 8);
        const float4* mu1 = (const float4*)(mh + (size_t)C_SEG * 8 + u * 8);
        const float4* mv1 = (const float4*)(mh + (size_t)C_SEG * 8 + vv * 8);
        float dot = 0.0f;
#pragma unroll
        for (int j = 0; j < 2; ++j) {
            const float4 a = mu0[j];
            const float4 bb = mv0[j];
            dot = fmaf(a.x, bb.x, dot);
            dot = fmaf(a.y, bb.y, dot);
            dot = fmaf(a.z, bb.z, dot);
            dot = fmaf(a.w, bb.w, dot);
        }
#pragma unroll
        for (int j = 0; j < 2; ++j) {
            const float4 a = mu1[j];
            const float4 bb = mv1[j];
            dot = fmaf(a.x, bb.x, dot);
            dot = fmaf(a.y, bb.y, dot);
            dot = fmaf(a.z, bb.z, dot);
            dot = fmaf(a.w, bb.w, dot);
        }
        const float d = 1.0f - invs[u] * invs[vv] * dot;
        v += fmaxf(1.5f - d * w[e2], 0.0f) * (1.0f / (float)NE_EDGES);
    }

    // ---- block reduction (16 waves) ----
    for (int o = 32; o > 0; o >>= 1) v += __shfl_down(v, o, 64);
    if ((t & 63) == 0) red[t >> 6] = v;
    __syncthreads();
    if (t == 0) {
        float s = 0.0f;
#pragma unroll
        for (int i = 0; i < 16; ++i) s += red[i];
        part[b] = s;
        __threadfence();
        tick = atomicAdd(counter, 1u);
    }
    __syncthreads();

    // ---- fused kF: last of 256 blocks sums part[] in index order ----
    if (tick == 255u) {
        __threadfence();
        float v2 = (t < 256) ? part[t] : 0.0f;
        for (int o = 32; o > 0; o >>= 1) v2 += __shfl_down(v2, o, 64);
        if ((t & 63) == 0) red[t >> 6] = v2;
        __syncthreads();
        if (t == 0) {
            float s = 0.0f;
#pragma unroll
            for (int i = 0; i < 16; ++i) s += red[i];
            out[0] = s;
            counter[0] = 0u;
        }
    }
}

extern "C" void kernel_launch(void* const* d_in, const int* in_sizes, int n_in,
                              void* d_out, int out_size, void* d_ws,
                              size_t ws_size, hipStream_t stream) {
    const float* emb = (const float*)d_in[0];      // (1,16,1024,1024) fp32
    const float* weights = (const float*)d_in[1];  // (16384,) fp32
    const int* seg = (const int*)d_in[2];          // (1,1,1024,1024) int32
    const int* edges = (const int*)d_in[3];        // (2,16384) int32
    float* out = (float*)d_out;

    char* ws = (char*)d_ws;
    float* sums_part = (float*)(ws);
    float* cnt_part = (float*)(ws + 0x800000);
    float* mh = (float*)(ws + 0x880000);
    float* invn = (float*)(ws + 0x8C0000);
    float* part = (float*)(ws + 0x8C4000);
    unsigned int* counter = (unsigned int*)(ws + 0x8C5000);

    dim3 gA(NCHUNK, 17);
    kA<<<gA, 512, 0, stream>>>(emb, seg, sums_part, cnt_part);
    kB<<<272, 256, 0, stream>>>(sums_part, cnt_part, mh, invn, counter);
    kC<<<256, 1024, 0, stream>>>(emb, seg, edges, weights, mh, invn, part, out, counter);
}